// Round 1
// baseline (186.608 us; speedup 1.0000x reference)
//
#include <hip/hip_runtime.h>

typedef _Float16 f16;
typedef _Float16 f16x8 __attribute__((ext_vector_type(8)));
typedef _Float16 f16x4 __attribute__((ext_vector_type(4)));
typedef float f32x4 __attribute__((ext_vector_type(4)));

#define MDIM 128
#define NDIM 256
#define CDIM 256
#define ROWS (MDIM*NDIM)   // 32768

// ---------------- K1: LayerNorm -> fp16 ----------------
// one wave per row of 256 channels; float4 loads; full-wave shuffle reduce
__global__ __launch_bounds__(256) void k_ln(const float* __restrict__ x,
                                            const float* __restrict__ g,
                                            const float* __restrict__ b,
                                            f16* __restrict__ y)
{
  int row  = blockIdx.x * 4 + (threadIdx.x >> 6);
  int lane = threadIdx.x & 63;
  const float4 xv = *(const float4*)(x + (size_t)row * CDIM + lane * 4);
  float s  = xv.x + xv.y + xv.z + xv.w;
  float s2 = xv.x*xv.x + xv.y*xv.y + xv.z*xv.z + xv.w*xv.w;
#pragma unroll
  for (int m = 1; m < 64; m <<= 1) {
    s  += __shfl_xor(s,  m, 64);
    s2 += __shfl_xor(s2, m, 64);
  }
  float mu  = s * (1.0f / CDIM);
  float var = s2 * (1.0f / CDIM) - mu * mu;
  float rs  = rsqrtf(var + 1e-5f);
  const float4 gv = *(const float4*)(g + lane * 4);
  const float4 bv = *(const float4*)(b + lane * 4);
  f16x4 o;
  o[0] = (f16)((xv.x - mu) * rs * gv.x + bv.x);
  o[1] = (f16)((xv.y - mu) * rs * gv.y + bv.y);
  o[2] = (f16)((xv.z - mu) * rs * gv.z + bv.z);
  o[3] = (f16)((xv.w - mu) * rs * gv.w + bv.w);
  *(f16x4*)(y + (size_t)row * CDIM + lane * 4) = o;
}

// ---------------- K2: QKV projection GEMM ----------------
// C[32768 x 768] = X[32768 x 256] @ [wq|wk|wv]; 64x64 tile, 4 waves 2x2,
// each wave 32x32 (2x2 16x16x32 f16 MFMA frags), K-step 32.
__global__ __launch_bounds__(256) void k_qkv(const f16* __restrict__ x,
    const float* __restrict__ wq, const float* __restrict__ wk, const float* __restrict__ wv,
    f16* __restrict__ q, f16* __restrict__ k, f16* __restrict__ v)
{
  __shared__ f16 As[64][40];   // [row][k], +8 pad
  __shared__ f16 Bt[64][40];   // [col][k] (B transposed), +8 pad
  int bm  = blockIdx.x;
  int gc0 = blockIdx.y * 64;               // 0..704
  int t = threadIdx.x, lane = t & 63, w = t >> 6;
  int wr = w >> 1, wc = w & 1;
  const float* W = (gc0 < 256) ? wq : (gc0 < 512) ? wk : wv;
  f16* dst       = (gc0 < 256) ? q  : (gc0 < 512) ? k  : v;
  int wc0 = gc0 & 255;
  f32x4 acc[2][2] = {};
  for (int kt = 0; kt < 8; ++kt) {
    {
      int r = t >> 2, c = (t & 3) * 8;
      *(f16x8*)&As[r][c] = *(const f16x8*)(x + (size_t)(bm * 64 + r) * CDIM + kt * 32 + c);
    }
    {
      int c = t & 63, kc = (t >> 6) * 8;
      f16x8 bvv;
#pragma unroll
      for (int i = 0; i < 8; ++i)
        bvv[i] = (f16)W[(size_t)(kt * 32 + kc + i) * 256 + wc0 + c];
      *(f16x8*)&Bt[c][kc] = bvv;
    }
    __syncthreads();
    f16x8 a0 = *(const f16x8*)&As[wr * 32 +      (lane & 15)][(lane >> 4) * 8];
    f16x8 a1 = *(const f16x8*)&As[wr * 32 + 16 + (lane & 15)][(lane >> 4) * 8];
    f16x8 b0 = *(const f16x8*)&Bt[wc * 32 +      (lane & 15)][(lane >> 4) * 8];
    f16x8 b1 = *(const f16x8*)&Bt[wc * 32 + 16 + (lane & 15)][(lane >> 4) * 8];
    acc[0][0] = __builtin_amdgcn_mfma_f32_16x16x32_f16(a0, b0, acc[0][0], 0, 0, 0);
    acc[0][1] = __builtin_amdgcn_mfma_f32_16x16x32_f16(a0, b1, acc[0][1], 0, 0, 0);
    acc[1][0] = __builtin_amdgcn_mfma_f32_16x16x32_f16(a1, b0, acc[1][0], 0, 0, 0);
    acc[1][1] = __builtin_amdgcn_mfma_f32_16x16x32_f16(a1, b1, acc[1][1], 0, 0, 0);
    __syncthreads();
  }
#pragma unroll
  for (int mi = 0; mi < 2; ++mi)
#pragma unroll
    for (int ni = 0; ni < 2; ++ni)
#pragma unroll
      for (int r = 0; r < 4; ++r) {
        int row = bm * 64 + wr * 32 + mi * 16 + (lane >> 4) * 4 + r;
        int col = wc0 + wc * 32 + ni * 16 + (lane & 15);
        dst[(size_t)row * 256 + col] = (f16)acc[mi][ni][r];
      }
}

// ---------------- K3: per-(m,h) attention ----------------
// block = (m,h); 4 waves; each wave owns 64 query rows, processed in 16-row
// chunks. S = q@k^T (one K=32 MFMA per 16x16 frag), fp32 softmax over j via
// 16-lane shfl groups, P staged to per-wave LDS, PV = 8 k-steps x 2 col frags.
__global__ __launch_bounds__(256) void k_attn(const f16* __restrict__ q,
    const f16* __restrict__ k, const f16* __restrict__ v, f16* __restrict__ o)
{
  __shared__ f16 qs[256][40];      // [n][c] head slice
  __shared__ f16 ks[256][40];      // [n][c]
  __shared__ f16 vt[32][264];      // [c][n] (transposed)
  __shared__ f16 ps[4][16][264];   // per-wave P chunk [i][j]
  int m = blockIdx.x >> 3, h = blockIdx.x & 7;
  int t = threadIdx.x, lane = t & 63, w = t >> 6;
  size_t base = (size_t)m * 256 * 256;
  // gather head-h slices (stride-8 f16 reads, L2-resident)
  for (int c = 0; c < 32; ++c) {
    int n = t;
    qs[n][c] = q[base + (size_t)n * 256 + c * 8 + h];
    ks[n][c] = k[base + (size_t)n * 256 + c * 8 + h];
    vt[c][n] = v[base + (size_t)n * 256 + c * 8 + h];
  }
  __syncthreads();
  const float scale = 0.17677669529663689f;  // 1/sqrt(32)
  for (int chunk = 0; chunk < 4; ++chunk) {
    int i0 = w * 64 + chunk * 16;
    f16x8 qa = *(const f16x8*)&qs[i0 + (lane & 15)][(lane >> 4) * 8];
    f32x4 s[16];
#pragma unroll
    for (int jf = 0; jf < 16; ++jf) {
      f16x8 kb = *(const f16x8*)&ks[jf * 16 + (lane & 15)][(lane >> 4) * 8];
      f32x4 z = {0.f, 0.f, 0.f, 0.f};
      s[jf] = __builtin_amdgcn_mfma_f32_16x16x32_f16(qa, kb, z, 0, 0, 0);
    }
#pragma unroll
    for (int r = 0; r < 4; ++r) {
      float mx = -1e30f;
#pragma unroll
      for (int jf = 0; jf < 16; ++jf) mx = fmaxf(mx, s[jf][r]);
      mx = fmaxf(mx, __shfl_xor(mx, 1, 64));
      mx = fmaxf(mx, __shfl_xor(mx, 2, 64));
      mx = fmaxf(mx, __shfl_xor(mx, 4, 64));
      mx = fmaxf(mx, __shfl_xor(mx, 8, 64));
      float ev[16]; float sum = 0.f;
#pragma unroll
      for (int jf = 0; jf < 16; ++jf) { ev[jf] = __expf((s[jf][r] - mx) * scale); sum += ev[jf]; }
      sum += __shfl_xor(sum, 1, 64);
      sum += __shfl_xor(sum, 2, 64);
      sum += __shfl_xor(sum, 4, 64);
      sum += __shfl_xor(sum, 8, 64);
      float inv = 1.f / sum;
#pragma unroll
      for (int jf = 0; jf < 16; ++jf)
        ps[w][(lane >> 4) * 4 + r][jf * 16 + (lane & 15)] = (f16)(ev[jf] * inv);
    }
    // PV: out[16 x 32] = P[16 x 256] @ V[256 x 32]
    f32x4 oa0 = {0.f,0.f,0.f,0.f}, oa1 = {0.f,0.f,0.f,0.f};
#pragma unroll
    for (int kk = 0; kk < 8; ++kk) {
      f16x8 pa  = *(const f16x8*)&ps[w][lane & 15][kk * 32 + (lane >> 4) * 8];
      f16x8 vb0 = *(const f16x8*)&vt[(lane & 15)][kk * 32 + (lane >> 4) * 8];
      f16x8 vb1 = *(const f16x8*)&vt[16 + (lane & 15)][kk * 32 + (lane >> 4) * 8];
      oa0 = __builtin_amdgcn_mfma_f32_16x16x32_f16(pa, vb0, oa0, 0, 0, 0);
      oa1 = __builtin_amdgcn_mfma_f32_16x16x32_f16(pa, vb1, oa1, 0, 0, 0);
    }
#pragma unroll
    for (int r = 0; r < 4; ++r) {
      int i = i0 + (lane >> 4) * 4 + r;
      int c0 = (lane & 15);
      o[base + (size_t)i * 256 + (size_t)c0 * 8 + h]        = (f16)oa0[r];
      o[base + (size_t)i * 256 + (size_t)(16 + c0) * 8 + h] = (f16)oa1[r];
    }
  }
}

// ---------------- K4: output projection ----------------
__global__ __launch_bounds__(256) void k_out(const f16* __restrict__ a,
    const float* __restrict__ wf, const float* __restrict__ bfv, float* __restrict__ out)
{
  __shared__ f16 As[64][40];
  __shared__ f16 Bt[64][40];
  int bm  = blockIdx.x;
  int gc0 = blockIdx.y * 64;
  int t = threadIdx.x, lane = t & 63, w = t >> 6;
  int wr = w >> 1, wc = w & 1;
  f32x4 acc[2][2] = {};
  for (int kt = 0; kt < 8; ++kt) {
    {
      int r = t >> 2, c = (t & 3) * 8;
      *(f16x8*)&As[r][c] = *(const f16x8*)(a + (size_t)(bm * 64 + r) * 256 + kt * 32 + c);
    }
    {
      int c = t & 63, kc = (t >> 6) * 8;
      f16x8 bvv;
#pragma unroll
      for (int i = 0; i < 8; ++i)
        bvv[i] = (f16)wf[(size_t)(kt * 32 + kc + i) * 256 + gc0 + c];
      *(f16x8*)&Bt[c][kc] = bvv;
    }
    __syncthreads();
    f16x8 a0 = *(const f16x8*)&As[wr * 32 +      (lane & 15)][(lane >> 4) * 8];
    f16x8 a1 = *(const f16x8*)&As[wr * 32 + 16 + (lane & 15)][(lane >> 4) * 8];
    f16x8 b0 = *(const f16x8*)&Bt[wc * 32 +      (lane & 15)][(lane >> 4) * 8];
    f16x8 b1 = *(const f16x8*)&Bt[wc * 32 + 16 + (lane & 15)][(lane >> 4) * 8];
    acc[0][0] = __builtin_amdgcn_mfma_f32_16x16x32_f16(a0, b0, acc[0][0], 0, 0, 0);
    acc[0][1] = __builtin_amdgcn_mfma_f32_16x16x32_f16(a0, b1, acc[0][1], 0, 0, 0);
    acc[1][0] = __builtin_amdgcn_mfma_f32_16x16x32_f16(a1, b0, acc[1][0], 0, 0, 0);
    acc[1][1] = __builtin_amdgcn_mfma_f32_16x16x32_f16(a1, b1, acc[1][1], 0, 0, 0);
    __syncthreads();
  }
#pragma unroll
  for (int mi = 0; mi < 2; ++mi)
#pragma unroll
    for (int ni = 0; ni < 2; ++ni)
#pragma unroll
      for (int r = 0; r < 4; ++r) {
        int row = bm * 64 + wr * 32 + mi * 16 + (lane >> 4) * 4 + r;
        int col = gc0 + wc * 32 + ni * 16 + (lane & 15);
        out[(size_t)row * 256 + col] = acc[mi][ni][r] + bfv[col];
      }
}

extern "C" void kernel_launch(void* const* d_in, const int* in_sizes, int n_in,
                              void* d_out, int out_size, void* d_ws, size_t ws_size,
                              hipStream_t stream)
{
  const float* x  = (const float*)d_in[0];
  const float* g  = (const float*)d_in[1];
  const float* b  = (const float*)d_in[2];
  const float* wq = (const float*)d_in[3];
  const float* wk = (const float*)d_in[4];
  const float* wv = (const float*)d_in[5];
  const float* wf = (const float*)d_in[6];
  const float* bf = (const float*)d_in[7];
  float* out = (float*)d_out;

  // ws layout: 5 x 16 MiB fp16 [32768 x 256] buffers (80 MiB total)
  char* ws = (char*)d_ws;
  f16* xh = (f16*)(ws);
  f16* qh = (f16*)(ws + (size_t)16 * 1024 * 1024);
  f16* kh = (f16*)(ws + (size_t)32 * 1024 * 1024);
  f16* vh = (f16*)(ws + (size_t)48 * 1024 * 1024);
  f16* ah = (f16*)(ws + (size_t)64 * 1024 * 1024);

  k_ln  <<<ROWS / 4,           256, 0, stream>>>(x, g, b, xh);
  k_qkv <<<dim3(ROWS / 64, 12), 256, 0, stream>>>(xh, wq, wk, wv, qh, kh, vh);
  k_attn<<<MDIM * 8,           256, 0, stream>>>(qh, kh, vh, ah);
  k_out <<<dim3(ROWS / 64, 4), 256, 0, stream>>>(ah, wf, bf, out);
}

// Round 2
// 98.378 us; speedup vs baseline: 1.8969x; 1.8969x over previous
//
#include <hip/hip_runtime.h>

typedef _Float16 f16;
typedef _Float16 f16x8 __attribute__((ext_vector_type(8)));
typedef _Float16 f16x4 __attribute__((ext_vector_type(4)));
typedef float f32x4 __attribute__((ext_vector_type(4)));

#define MDIM 128
#define NDIM 256
#define CDIM 256
#define ROWS (MDIM*NDIM)   // 32768

// ---------------- K0: weight prepack ----------------
// Repack wq/wk/wv into f16 [je][k] (transposed, column-permuted je=h*32+c,
// i.e. original col j=(je&31)*8+(je>>5)); softmax scale folded into wq.
// Repack wf into f16 [col][ke] with row-permutation perm(ke)=(ke&31)*8+(ke>>5).
__global__ __launch_bounds__(256) void k_prep(
    const float* __restrict__ wq, const float* __restrict__ wk,
    const float* __restrict__ wv, const float* __restrict__ wf,
    f16* __restrict__ bq, f16* __restrict__ bk, f16* __restrict__ bv,
    f16* __restrict__ bw)
{
  int idx   = blockIdx.x & 255;
  int which = blockIdx.x >> 8;
  int kk    = threadIdx.x;
  if (which < 3) {
    const float* W = which == 0 ? wq : which == 1 ? wk : wv;
    f16* dst       = which == 0 ? bq : which == 1 ? bk : bv;
    float sc = which == 0 ? 0.17677669529663689f : 1.0f;  // 1/sqrt(32) into q
    int j = (idx & 31) * 8 + (idx >> 5);
    dst[idx * 256 + kk] = (f16)(W[(size_t)kk * 256 + j] * sc);
  } else {
    int pk = (kk & 31) * 8 + (kk >> 5);
    bw[idx * 256 + kk] = (f16)wf[(size_t)pk * 256 + idx];
  }
}

// ---------------- K1: LayerNorm -> fp16 ----------------
__global__ __launch_bounds__(256) void k_ln(const float* __restrict__ x,
                                            const float* __restrict__ g,
                                            const float* __restrict__ b,
                                            f16* __restrict__ y)
{
  int row  = blockIdx.x * 4 + (threadIdx.x >> 6);
  int lane = threadIdx.x & 63;
  const float4 xv = *(const float4*)(x + (size_t)row * CDIM + lane * 4);
  float s  = xv.x + xv.y + xv.z + xv.w;
  float s2 = xv.x*xv.x + xv.y*xv.y + xv.z*xv.z + xv.w*xv.w;
#pragma unroll
  for (int m = 1; m < 64; m <<= 1) {
    s  += __shfl_xor(s,  m, 64);
    s2 += __shfl_xor(s2, m, 64);
  }
  float mu  = s * (1.0f / CDIM);
  float var = s2 * (1.0f / CDIM) - mu * mu;
  float rs  = rsqrtf(var + 1e-5f);
  const float4 gv = *(const float4*)(g + lane * 4);
  const float4 bv = *(const float4*)(b + lane * 4);
  f16x4 o;
  o[0] = (f16)((xv.x - mu) * rs * gv.x + bv.x);
  o[1] = (f16)((xv.y - mu) * rs * gv.y + bv.y);
  o[2] = (f16)((xv.z - mu) * rs * gv.z + bv.z);
  o[3] = (f16)((xv.w - mu) * rs * gv.w + bv.w);
  *(f16x4*)(y + (size_t)row * CDIM + lane * 4) = o;
}

// ---------------- K2: QKV projection GEMM ----------------
// Per block: 64 rows, whole K=256 of A in LDS; loop 12 col-tiles (q,k,v x 4),
// staging prepacked f16 B[64][256] per tile. 4 waves 2x2, wave tile 32x32.
__global__ __launch_bounds__(256) void k_qkv(const f16* __restrict__ x,
    const f16* __restrict__ bq, const f16* __restrict__ bk, const f16* __restrict__ bv,
    f16* __restrict__ q, f16* __restrict__ k, f16* __restrict__ v)
{
  __shared__ f16 As[64][264];   // row stride 528B: 16-aligned, 2-way banks max
  __shared__ f16 Bs[64][264];
  int bm = blockIdx.x;
  int t = threadIdx.x, lane = t & 63, w = t >> 6;
  int wr = w >> 1, wc = w & 1;
  int l15 = lane & 15, l4 = lane >> 4;
#pragma unroll
  for (int p = 0; p < 8; ++p) {
    int r = t >> 2, c0 = (t & 3) * 8 + p * 32;
    *(f16x8*)&As[r][c0] = *(const f16x8*)(x + (size_t)(bm * 64 + r) * 256 + c0);
  }
  for (int ct = 0; ct < 12; ++ct) {
    const f16* B = ct < 4 ? bq : ct < 8 ? bk : bv;
    f16* dst     = ct < 4 ? q  : ct < 8 ? k  : v;
    int je0 = (ct & 3) * 64;
#pragma unroll
    for (int p = 0; p < 8; ++p) {
      int r = t >> 2, c0 = (t & 3) * 8 + p * 32;
      *(f16x8*)&Bs[r][c0] = *(const f16x8*)(B + (size_t)(je0 + r) * 256 + c0);
    }
    __syncthreads();
    f32x4 acc[2][2] = {};
#pragma unroll
    for (int kt = 0; kt < 8; ++kt) {
      f16x8 a0 = *(const f16x8*)&As[wr * 32 +      l15][kt * 32 + l4 * 8];
      f16x8 a1 = *(const f16x8*)&As[wr * 32 + 16 + l15][kt * 32 + l4 * 8];
      f16x8 b0 = *(const f16x8*)&Bs[wc * 32 +      l15][kt * 32 + l4 * 8];
      f16x8 b1 = *(const f16x8*)&Bs[wc * 32 + 16 + l15][kt * 32 + l4 * 8];
      acc[0][0] = __builtin_amdgcn_mfma_f32_16x16x32_f16(a0, b0, acc[0][0], 0, 0, 0);
      acc[0][1] = __builtin_amdgcn_mfma_f32_16x16x32_f16(a0, b1, acc[0][1], 0, 0, 0);
      acc[1][0] = __builtin_amdgcn_mfma_f32_16x16x32_f16(a1, b0, acc[1][0], 0, 0, 0);
      acc[1][1] = __builtin_amdgcn_mfma_f32_16x16x32_f16(a1, b1, acc[1][1], 0, 0, 0);
    }
#pragma unroll
    for (int mi = 0; mi < 2; ++mi)
#pragma unroll
      for (int ni = 0; ni < 2; ++ni)
#pragma unroll
        for (int r = 0; r < 4; ++r) {
          int row = bm * 64 + wr * 32 + mi * 16 + l4 * 4 + r;
          int col = je0 + wc * 32 + ni * 16 + l15;
          dst[(size_t)row * 256 + col] = (f16)acc[mi][ni][r];
        }
    __syncthreads();   // guard Bs overwrite
  }
}

// ---------------- K3: per-(m,h) attention ----------------
// Layout [row][h*32+c]: all loads 64B-contiguous per row. Q direct to frags
// from global (no LDS). K,V staged once; per-wave private P buffer.
__global__ __launch_bounds__(256) void k_attn(const f16* __restrict__ q,
    const f16* __restrict__ k, const f16* __restrict__ v, f16* __restrict__ o)
{
  __shared__ f16 ks[256][40];      // 20.0 KB
  __shared__ f16 vt[32][264];      // 16.5 KB (V transposed [c][n])
  __shared__ f16 ps[4][16][264];   // 33.0 KB per-wave P chunks
  int m = blockIdx.x >> 3, h = blockIdx.x & 7;
  int t = threadIdx.x, lane = t & 63, w = t >> 6;
  int l15 = lane & 15, l4 = lane >> 4;
  size_t base = ((size_t)m * 256) * 256 + h * 32;   // + n*256 + c
  // stage K (vector) and V (transpose scatter)
#pragma unroll
  for (int p = 0; p < 4; ++p) {
    int n = p * 64 + (t >> 2);
    int c0 = (t & 3) * 8;
    *(f16x8*)&ks[n][c0] = *(const f16x8*)(k + base + (size_t)n * 256 + c0);
    f16x8 vv = *(const f16x8*)(v + base + (size_t)n * 256 + c0);
#pragma unroll
    for (int i = 0; i < 8; ++i) vt[c0 + i][n] = vv[i];
  }
  __syncthreads();
  for (int ch = 0; ch < 4; ++ch) {
    int i0 = w * 64 + ch * 16;
    f16x8 qa = *(const f16x8*)(q + base + (size_t)(i0 + l15) * 256 + l4 * 8);
    f32x4 s[16];
#pragma unroll
    for (int jf = 0; jf < 16; ++jf) {
      f16x8 kb = *(const f16x8*)&ks[jf * 16 + l15][l4 * 8];
      f32x4 z = {0.f, 0.f, 0.f, 0.f};
      s[jf] = __builtin_amdgcn_mfma_f32_16x16x32_f16(qa, kb, z, 0, 0, 0);
    }
#pragma unroll
    for (int r = 0; r < 4; ++r) {
      float mx = s[0][r];
#pragma unroll
      for (int jf = 1; jf < 16; ++jf) mx = fmaxf(mx, s[jf][r]);
      mx = fmaxf(mx, __shfl_xor(mx, 1, 64));
      mx = fmaxf(mx, __shfl_xor(mx, 2, 64));
      mx = fmaxf(mx, __shfl_xor(mx, 4, 64));
      mx = fmaxf(mx, __shfl_xor(mx, 8, 64));
      float sum = 0.f;
#pragma unroll
      for (int jf = 0; jf < 16; ++jf) {
        float e = __expf(s[jf][r] - mx);   // scale folded into wq
        s[jf][r] = e;
        sum += e;
      }
      sum += __shfl_xor(sum, 1, 64);
      sum += __shfl_xor(sum, 2, 64);
      sum += __shfl_xor(sum, 4, 64);
      sum += __shfl_xor(sum, 8, 64);
      float inv = 1.f / sum;
#pragma unroll
      for (int jf = 0; jf < 16; ++jf)
        ps[w][l4 * 4 + r][jf * 16 + l15] = (f16)(s[jf][r] * inv);
    }
    // PV: out[16x32] = P[16x256] @ V[256x32]
    f32x4 o0 = {0.f,0.f,0.f,0.f}, o1 = {0.f,0.f,0.f,0.f};
#pragma unroll
    for (int kk = 0; kk < 8; ++kk) {
      f16x8 pa  = *(const f16x8*)&ps[w][l15][kk * 32 + l4 * 8];
      f16x8 vb0 = *(const f16x8*)&vt[l15][kk * 32 + l4 * 8];
      f16x8 vb1 = *(const f16x8*)&vt[16 + l15][kk * 32 + l4 * 8];
      o0 = __builtin_amdgcn_mfma_f32_16x16x32_f16(pa, vb0, o0, 0, 0, 0);
      o1 = __builtin_amdgcn_mfma_f32_16x16x32_f16(pa, vb1, o1, 0, 0, 0);
    }
#pragma unroll
    for (int r = 0; r < 4; ++r) {
      size_t ro = base + (size_t)(i0 + l4 * 4 + r) * 256;
      o[ro + l15]      = (f16)o0[r];
      o[ro + 16 + l15] = (f16)o1[r];
    }
  }
}

// ---------------- K4: output projection ----------------
__global__ __launch_bounds__(256) void k_out(const f16* __restrict__ a,
    const f16* __restrict__ bw, const float* __restrict__ bias,
    float* __restrict__ out)
{
  __shared__ f16 As[64][264];
  __shared__ f16 Bs[64][264];
  int bm = blockIdx.x;
  int t = threadIdx.x, lane = t & 63, w = t >> 6;
  int wr = w >> 1, wc = w & 1;
  int l15 = lane & 15, l4 = lane >> 4;
#pragma unroll
  for (int p = 0; p < 8; ++p) {
    int r = t >> 2, c0 = (t & 3) * 8 + p * 32;
    *(f16x8*)&As[r][c0] = *(const f16x8*)(a + (size_t)(bm * 64 + r) * 256 + c0);
  }
  for (int ct = 0; ct < 4; ++ct) {
    int col0 = ct * 64;
#pragma unroll
    for (int p = 0; p < 8; ++p) {
      int r = t >> 2, c0 = (t & 3) * 8 + p * 32;
      *(f16x8*)&Bs[r][c0] = *(const f16x8*)(bw + (size_t)(col0 + r) * 256 + c0);
    }
    __syncthreads();
    f32x4 acc[2][2] = {};
#pragma unroll
    for (int kt = 0; kt < 8; ++kt) {
      f16x8 a0 = *(const f16x8*)&As[wr * 32 +      l15][kt * 32 + l4 * 8];
      f16x8 a1 = *(const f16x8*)&As[wr * 32 + 16 + l15][kt * 32 + l4 * 8];
      f16x8 b0 = *(const f16x8*)&Bs[wc * 32 +      l15][kt * 32 + l4 * 8];
      f16x8 b1 = *(const f16x8*)&Bs[wc * 32 + 16 + l15][kt * 32 + l4 * 8];
      acc[0][0] = __builtin_amdgcn_mfma_f32_16x16x32_f16(a0, b0, acc[0][0], 0, 0, 0);
      acc[0][1] = __builtin_amdgcn_mfma_f32_16x16x32_f16(a0, b1, acc[0][1], 0, 0, 0);
      acc[1][0] = __builtin_amdgcn_mfma_f32_16x16x32_f16(a1, b0, acc[1][0], 0, 0, 0);
      acc[1][1] = __builtin_amdgcn_mfma_f32_16x16x32_f16(a1, b1, acc[1][1], 0, 0, 0);
    }
#pragma unroll
    for (int mi = 0; mi < 2; ++mi)
#pragma unroll
      for (int ni = 0; ni < 2; ++ni)
#pragma unroll
        for (int r = 0; r < 4; ++r) {
          int row = bm * 64 + wr * 32 + mi * 16 + l4 * 4 + r;
          int col = col0 + wc * 32 + ni * 16 + l15;
          out[(size_t)row * 256 + col] = acc[mi][ni][r] + bias[col];
        }
    __syncthreads();
  }
}

extern "C" void kernel_launch(void* const* d_in, const int* in_sizes, int n_in,
                              void* d_out, int out_size, void* d_ws, size_t ws_size,
                              hipStream_t stream)
{
  const float* x  = (const float*)d_in[0];
  const float* g  = (const float*)d_in[1];
  const float* b  = (const float*)d_in[2];
  const float* wq = (const float*)d_in[3];
  const float* wk = (const float*)d_in[4];
  const float* wv = (const float*)d_in[5];
  const float* wf = (const float*)d_in[6];
  const float* bf = (const float*)d_in[7];
  float* out = (float*)d_out;

  // ws: xh/ah share [0,16M); qh,kh,vh; then 4x128KB prepacked weights
  char* ws = (char*)d_ws;
  f16* xh = (f16*)(ws);                                  // also attn output
  f16* qh = (f16*)(ws + (size_t)16 * 1024 * 1024);
  f16* kh = (f16*)(ws + (size_t)32 * 1024 * 1024);
  f16* vh = (f16*)(ws + (size_t)48 * 1024 * 1024);
  char* wbase = ws + (size_t)64 * 1024 * 1024;
  f16* bq = (f16*)(wbase);
  f16* bk = (f16*)(wbase + 128 * 1024);
  f16* bv = (f16*)(wbase + 256 * 1024);
  f16* bw = (f16*)(wbase + 384 * 1024);

  k_prep<<<1024,      256, 0, stream>>>(wq, wk, wv, wf, bq, bk, bv, bw);
  k_ln  <<<ROWS / 4,  256, 0, stream>>>(x, g, b, xh);
  k_qkv <<<ROWS / 64, 256, 0, stream>>>(xh, bq, bk, bv, qh, kh, vh);
  k_attn<<<MDIM * 8,  256, 0, stream>>>(qh, kh, vh, xh);
  k_out <<<ROWS / 64, 256, 0, stream>>>(xh, bw, bf, out);
}

// Round 3
// 98.294 us; speedup vs baseline: 1.8985x; 1.0008x over previous
//
#include <hip/hip_runtime.h>

typedef _Float16 f16;
typedef _Float16 f16x8 __attribute__((ext_vector_type(8)));
typedef _Float16 f16x4 __attribute__((ext_vector_type(4)));
typedef float f32x4 __attribute__((ext_vector_type(4)));

#define MDIM 128
#define NDIM 256
#define CDIM 256
#define ROWS (MDIM*NDIM)   // 32768

// ---------------- K0: weight prepack ----------------
// Repack wq/wk/wv into f16 [je][k] (transposed, column-permuted je=h*32+c,
// i.e. original col j=(je&31)*8+(je>>5)); softmax scale folded into wq.
// Repack wf into f16 [col][ke] with row-permutation perm(ke)=(ke&31)*8+(ke>>5).
__global__ __launch_bounds__(256) void k_prep(
    const float* __restrict__ wq, const float* __restrict__ wk,
    const float* __restrict__ wv, const float* __restrict__ wf,
    f16* __restrict__ bq, f16* __restrict__ bk, f16* __restrict__ bv,
    f16* __restrict__ bw)
{
  int idx   = blockIdx.x & 255;
  int which = blockIdx.x >> 8;
  int kk    = threadIdx.x;
  if (which < 3) {
    const float* W = which == 0 ? wq : which == 1 ? wk : wv;
    f16* dst       = which == 0 ? bq : which == 1 ? bk : bv;
    float sc = which == 0 ? 0.17677669529663689f : 1.0f;  // 1/sqrt(32) into q
    int j = (idx & 31) * 8 + (idx >> 5);
    dst[idx * 256 + kk] = (f16)(W[(size_t)kk * 256 + j] * sc);
  } else {
    int pk = (kk & 31) * 8 + (kk >> 5);
    bw[idx * 256 + kk] = (f16)wf[(size_t)pk * 256 + idx];
  }
}

// ---------------- K1: LayerNorm -> fp16 ----------------
__global__ __launch_bounds__(256) void k_ln(const float* __restrict__ x,
                                            const float* __restrict__ g,
                                            const float* __restrict__ b,
                                            f16* __restrict__ y)
{
  int row  = blockIdx.x * 4 + (threadIdx.x >> 6);
  int lane = threadIdx.x & 63;
  const float4 xv = *(const float4*)(x + (size_t)row * CDIM + lane * 4);
  float s  = xv.x + xv.y + xv.z + xv.w;
  float s2 = xv.x*xv.x + xv.y*xv.y + xv.z*xv.z + xv.w*xv.w;
#pragma unroll
  for (int m = 1; m < 64; m <<= 1) {
    s  += __shfl_xor(s,  m, 64);
    s2 += __shfl_xor(s2, m, 64);
  }
  float mu  = s * (1.0f / CDIM);
  float var = s2 * (1.0f / CDIM) - mu * mu;
  float rs  = rsqrtf(var + 1e-5f);
  const float4 gv = *(const float4*)(g + lane * 4);
  const float4 bv = *(const float4*)(b + lane * 4);
  f16x4 o;
  o[0] = (f16)((xv.x - mu) * rs * gv.x + bv.x);
  o[1] = (f16)((xv.y - mu) * rs * gv.y + bv.y);
  o[2] = (f16)((xv.z - mu) * rs * gv.z + bv.z);
  o[3] = (f16)((xv.w - mu) * rs * gv.w + bv.w);
  *(f16x4*)(y + (size_t)row * CDIM + lane * 4) = o;
}

// ---------------- K2: QKV projection GEMM ----------------
// Per block: 64 rows, whole K=256 of A in LDS; loop 12 col-tiles (q,k,v x 4),
// staging prepacked f16 B[64][256] per tile. 4 waves 2x2, wave tile 32x32.
__global__ __launch_bounds__(256) void k_qkv(const f16* __restrict__ x,
    const f16* __restrict__ bq, const f16* __restrict__ bk, const f16* __restrict__ bv,
    f16* __restrict__ q, f16* __restrict__ k, f16* __restrict__ v)
{
  __shared__ f16 As[64][264];   // row stride 528B: 16-aligned, 2-way banks max
  __shared__ f16 Bs[64][264];
  int bm = blockIdx.x;
  int t = threadIdx.x, lane = t & 63, w = t >> 6;
  int wr = w >> 1, wc = w & 1;
  int l15 = lane & 15, l4 = lane >> 4;
#pragma unroll
  for (int p = 0; p < 8; ++p) {
    int r = t >> 2, c0 = (t & 3) * 8 + p * 32;
    *(f16x8*)&As[r][c0] = *(const f16x8*)(x + (size_t)(bm * 64 + r) * 256 + c0);
  }
  for (int ct = 0; ct < 12; ++ct) {
    const f16* B = ct < 4 ? bq : ct < 8 ? bk : bv;
    f16* dst     = ct < 4 ? q  : ct < 8 ? k  : v;
    int je0 = (ct & 3) * 64;
#pragma unroll
    for (int p = 0; p < 8; ++p) {
      int r = t >> 2, c0 = (t & 3) * 8 + p * 32;
      *(f16x8*)&Bs[r][c0] = *(const f16x8*)(B + (size_t)(je0 + r) * 256 + c0);
    }
    __syncthreads();
    f32x4 acc[2][2] = {};
#pragma unroll
    for (int kt = 0; kt < 8; ++kt) {
      f16x8 a0 = *(const f16x8*)&As[wr * 32 +      l15][kt * 32 + l4 * 8];
      f16x8 a1 = *(const f16x8*)&As[wr * 32 + 16 + l15][kt * 32 + l4 * 8];
      f16x8 b0 = *(const f16x8*)&Bs[wc * 32 +      l15][kt * 32 + l4 * 8];
      f16x8 b1 = *(const f16x8*)&Bs[wc * 32 + 16 + l15][kt * 32 + l4 * 8];
      acc[0][0] = __builtin_amdgcn_mfma_f32_16x16x32_f16(a0, b0, acc[0][0], 0, 0, 0);
      acc[0][1] = __builtin_amdgcn_mfma_f32_16x16x32_f16(a0, b1, acc[0][1], 0, 0, 0);
      acc[1][0] = __builtin_amdgcn_mfma_f32_16x16x32_f16(a1, b0, acc[1][0], 0, 0, 0);
      acc[1][1] = __builtin_amdgcn_mfma_f32_16x16x32_f16(a1, b1, acc[1][1], 0, 0, 0);
    }
#pragma unroll
    for (int mi = 0; mi < 2; ++mi)
#pragma unroll
      for (int ni = 0; ni < 2; ++ni)
#pragma unroll
        for (int r = 0; r < 4; ++r) {
          int row = bm * 64 + wr * 32 + mi * 16 + l4 * 4 + r;
          int col = je0 + wc * 32 + ni * 16 + l15;
          dst[(size_t)row * 256 + col] = (f16)acc[mi][ni][r];
        }
    __syncthreads();   // guard Bs overwrite
  }
}

// ---------------- K3: per-(m,h) attention ----------------
// Layout [row][h*32+c]: all loads 64B-contiguous per row. Q direct to frags
// from global (no LDS). K,V staged once; per-wave private P buffer.
__global__ __launch_bounds__(256) void k_attn(const f16* __restrict__ q,
    const f16* __restrict__ k, const f16* __restrict__ v, f16* __restrict__ o)
{
  __shared__ f16 ks[256][40];      // 20.0 KB
  __shared__ f16 vt[32][264];      // 16.5 KB (V transposed [c][n])
  __shared__ f16 ps[4][16][264];   // 33.0 KB per-wave P chunks
  int m = blockIdx.x >> 3, h = blockIdx.x & 7;
  int t = threadIdx.x, lane = t & 63, w = t >> 6;
  int l15 = lane & 15, l4 = lane >> 4;
  size_t base = ((size_t)m * 256) * 256 + h * 32;   // + n*256 + c
  // stage K (vector) and V (transpose scatter)
#pragma unroll
  for (int p = 0; p < 4; ++p) {
    int n = p * 64 + (t >> 2);
    int c0 = (t & 3) * 8;
    *(f16x8*)&ks[n][c0] = *(const f16x8*)(k + base + (size_t)n * 256 + c0);
    f16x8 vv = *(const f16x8*)(v + base + (size_t)n * 256 + c0);
#pragma unroll
    for (int i = 0; i < 8; ++i) vt[c0 + i][n] = vv[i];
  }
  __syncthreads();
  for (int ch = 0; ch < 4; ++ch) {
    int i0 = w * 64 + ch * 16;
    f16x8 qa = *(const f16x8*)(q + base + (size_t)(i0 + l15) * 256 + l4 * 8);
    f32x4 s[16];
#pragma unroll
    for (int jf = 0; jf < 16; ++jf) {
      f16x8 kb = *(const f16x8*)&ks[jf * 16 + l15][l4 * 8];
      f32x4 z = {0.f, 0.f, 0.f, 0.f};
      s[jf] = __builtin_amdgcn_mfma_f32_16x16x32_f16(qa, kb, z, 0, 0, 0);
    }
#pragma unroll
    for (int r = 0; r < 4; ++r) {
      float mx = s[0][r];
#pragma unroll
      for (int jf = 1; jf < 16; ++jf) mx = fmaxf(mx, s[jf][r]);
      mx = fmaxf(mx, __shfl_xor(mx, 1, 64));
      mx = fmaxf(mx, __shfl_xor(mx, 2, 64));
      mx = fmaxf(mx, __shfl_xor(mx, 4, 64));
      mx = fmaxf(mx, __shfl_xor(mx, 8, 64));
      float sum = 0.f;
#pragma unroll
      for (int jf = 0; jf < 16; ++jf) {
        float e = __expf(s[jf][r] - mx);   // scale folded into wq
        s[jf][r] = e;
        sum += e;
      }
      sum += __shfl_xor(sum, 1, 64);
      sum += __shfl_xor(sum, 2, 64);
      sum += __shfl_xor(sum, 4, 64);
      sum += __shfl_xor(sum, 8, 64);
      float inv = 1.f / sum;
#pragma unroll
      for (int jf = 0; jf < 16; ++jf)
        ps[w][l4 * 4 + r][jf * 16 + l15] = (f16)(s[jf][r] * inv);
    }
    // PV: out[16x32] = P[16x256] @ V[256x32]
    f32x4 o0 = {0.f,0.f,0.f,0.f}, o1 = {0.f,0.f,0.f,0.f};
#pragma unroll
    for (int kk = 0; kk < 8; ++kk) {
      f16x8 pa  = *(const f16x8*)&ps[w][l15][kk * 32 + l4 * 8];
      f16x8 vb0 = *(const f16x8*)&vt[l15][kk * 32 + l4 * 8];
      f16x8 vb1 = *(const f16x8*)&vt[16 + l15][kk * 32 + l4 * 8];
      o0 = __builtin_amdgcn_mfma_f32_16x16x32_f16(pa, vb0, o0, 0, 0, 0);
      o1 = __builtin_amdgcn_mfma_f32_16x16x32_f16(pa, vb1, o1, 0, 0, 0);
    }
#pragma unroll
    for (int r = 0; r < 4; ++r) {
      size_t ro = base + (size_t)(i0 + l4 * 4 + r) * 256;
      o[ro + l15]      = (f16)o0[r];
      o[ro + 16 + l15] = (f16)o1[r];
    }
  }
}

// ---------------- K4: output projection ----------------
__global__ __launch_bounds__(256) void k_out(const f16* __restrict__ a,
    const f16* __restrict__ bw, const float* __restrict__ bias,
    float* __restrict__ out)
{
  __shared__ f16 As[64][264];
  __shared__ f16 Bs[64][264];
  int bm = blockIdx.x;
  int t = threadIdx.x, lane = t & 63, w = t >> 6;
  int wr = w >> 1, wc = w & 1;
  int l15 = lane & 15, l4 = lane >> 4;
#pragma unroll
  for (int p = 0; p < 8; ++p) {
    int r = t >> 2, c0 = (t & 3) * 8 + p * 32;
    *(f16x8*)&As[r][c0] = *(const f16x8*)(a + (size_t)(bm * 64 + r) * 256 + c0);
  }
  for (int ct = 0; ct < 4; ++ct) {
    int col0 = ct * 64;
#pragma unroll
    for (int p = 0; p < 8; ++p) {
      int r = t >> 2, c0 = (t & 3) * 8 + p * 32;
      *(f16x8*)&Bs[r][c0] = *(const f16x8*)(bw + (size_t)(col0 + r) * 256 + c0);
    }
    __syncthreads();
    f32x4 acc[2][2] = {};
#pragma unroll
    for (int kt = 0; kt < 8; ++kt) {
      f16x8 a0 = *(const f16x8*)&As[wr * 32 +      l15][kt * 32 + l4 * 8];
      f16x8 a1 = *(const f16x8*)&As[wr * 32 + 16 + l15][kt * 32 + l4 * 8];
      f16x8 b0 = *(const f16x8*)&Bs[wc * 32 +      l15][kt * 32 + l4 * 8];
      f16x8 b1 = *(const f16x8*)&Bs[wc * 32 + 16 + l15][kt * 32 + l4 * 8];
      acc[0][0] = __builtin_amdgcn_mfma_f32_16x16x32_f16(a0, b0, acc[0][0], 0, 0, 0);
      acc[0][1] = __builtin_amdgcn_mfma_f32_16x16x32_f16(a0, b1, acc[0][1], 0, 0, 0);
      acc[1][0] = __builtin_amdgcn_mfma_f32_16x16x32_f16(a1, b0, acc[1][0], 0, 0, 0);
      acc[1][1] = __builtin_amdgcn_mfma_f32_16x16x32_f16(a1, b1, acc[1][1], 0, 0, 0);
    }
#pragma unroll
    for (int mi = 0; mi < 2; ++mi)
#pragma unroll
      for (int ni = 0; ni < 2; ++ni)
#pragma unroll
        for (int r = 0; r < 4; ++r) {
          int row = bm * 64 + wr * 32 + mi * 16 + l4 * 4 + r;
          int col = col0 + wc * 32 + ni * 16 + l15;
          out[(size_t)row * 256 + col] = acc[mi][ni][r] + bias[col];
        }
    __syncthreads();
  }
}

extern "C" void kernel_launch(void* const* d_in, const int* in_sizes, int n_in,
                              void* d_out, int out_size, void* d_ws, size_t ws_size,
                              hipStream_t stream)
{
  const float* x  = (const float*)d_in[0];
  const float* g  = (const float*)d_in[1];
  const float* b  = (const float*)d_in[2];
  const float* wq = (const float*)d_in[3];
  const float* wk = (const float*)d_in[4];
  const float* wv = (const float*)d_in[5];
  const float* wf = (const float*)d_in[6];
  const float* bf = (const float*)d_in[7];
  float* out = (float*)d_out;

  // ws: xh/ah share [0,16M); qh,kh,vh; then 4x128KB prepacked weights
  char* ws = (char*)d_ws;
  f16* xh = (f16*)(ws);                                  // also attn output
  f16* qh = (f16*)(ws + (size_t)16 * 1024 * 1024);
  f16* kh = (f16*)(ws + (size_t)32 * 1024 * 1024);
  f16* vh = (f16*)(ws + (size_t)48 * 1024 * 1024);
  char* wbase = ws + (size_t)64 * 1024 * 1024;
  f16* bq = (f16*)(wbase);
  f16* bk = (f16*)(wbase + 128 * 1024);
  f16* bv = (f16*)(wbase + 256 * 1024);
  f16* bw = (f16*)(wbase + 384 * 1024);

  k_prep<<<1024,      256, 0, stream>>>(wq, wk, wv, wf, bq, bk, bv, bw);
  k_ln  <<<ROWS / 4,  256, 0, stream>>>(x, g, b, xh);
  k_qkv <<<ROWS / 64, 256, 0, stream>>>(xh, bq, bk, bv, qh, kh, vh);
  k_attn<<<MDIM * 8,  256, 0, stream>>>(qh, kh, vh, xh);
  k_out <<<ROWS / 64, 256, 0, stream>>>(xh, bw, bf, out);
}

// Round 4
// 84.050 us; speedup vs baseline: 2.2202x; 1.1695x over previous
//
#include <hip/hip_runtime.h>

typedef _Float16 f16;
typedef _Float16 f16x8 __attribute__((ext_vector_type(8)));
typedef _Float16 f16x4 __attribute__((ext_vector_type(4)));
typedef _Float16 f16x2 __attribute__((ext_vector_type(2)));
typedef float f32x4 __attribute__((ext_vector_type(4)));
typedef float f32x16 __attribute__((ext_vector_type(16)));

#define MDIM 128
#define NDIM 256
#define CDIM 256
#define ROWS (MDIM*NDIM)   // 32768

// pack two f32 -> f16x2 in one int (k-ascending: low half = first element)
__device__ inline int pk2(float a, float b) {
  union { f16x2 h; int i; } u;
  u.h[0] = (f16)a; u.h[1] = (f16)b;
  return u.i;
}

// ---------------- K0: weight prepack ----------------
// wq/wk/wv -> f16 [je][k], je = h*32+c (orig col j=(je&31)*8+(je>>5)).
// wq additionally scaled by (1/sqrt(32))*log2(e) (exp2-domain softmax).
// wf -> f16 [col][ke], ke permuted the same way.
__global__ __launch_bounds__(256) void k_prep(
    const float* __restrict__ wq, const float* __restrict__ wk,
    const float* __restrict__ wv, const float* __restrict__ wf,
    f16* __restrict__ bq, f16* __restrict__ bk, f16* __restrict__ bv,
    f16* __restrict__ bw)
{
  int idx   = blockIdx.x & 255;
  int which = blockIdx.x >> 8;
  int kk    = threadIdx.x;
  if (which < 3) {
    const float* W = which == 0 ? wq : which == 1 ? wk : wv;
    f16* dst       = which == 0 ? bq : which == 1 ? bk : bv;
    float sc = which == 0 ? (0.17677669529663689f * 1.4426950408889634f) : 1.0f;
    int j = (idx & 31) * 8 + (idx >> 5);
    dst[idx * 256 + kk] = (f16)(W[(size_t)kk * 256 + j] * sc);
  } else {
    int pkk = (kk & 31) * 8 + (kk >> 5);
    bw[idx * 256 + kk] = (f16)wf[(size_t)pkk * 256 + idx];
  }
}

// ---------------- K1: fused LayerNorm + QKV GEMM ----------------
// Block = 64 rows. LN computes As[64][256] f16 in LDS directly. Then 12
// col-tiles (q,k x4 natural; v x4 transposed to vT[m][ch][n] via LDS bounce).
__global__ __launch_bounds__(256) void k_lnqkv(const float* __restrict__ x,
    const float* __restrict__ g, const float* __restrict__ bb,
    const f16* __restrict__ bq, const f16* __restrict__ bk, const f16* __restrict__ bv,
    f16* __restrict__ qo, f16* __restrict__ ko, f16* __restrict__ vT)
{
  __shared__ f16 As[64][264];
  __shared__ f16 Bs[64][264];
  __shared__ f16 vtmp[64][72];
  int bm = blockIdx.x;
  int t = threadIdx.x, lane = t & 63, w = t >> 6;
  int wr = w >> 1, wc = w & 1;
  int l15 = lane & 15, l4 = lane >> 4;
  // --- LN: wave w -> rows w*16..w*16+15, lane covers 4 channels ---
  const float4 gv  = *(const float4*)(g + lane * 4);
  const float4 bv4 = *(const float4*)(bb + lane * 4);
#pragma unroll 4
  for (int rr = 0; rr < 16; ++rr) {
    int r = w * 16 + rr;
    const float4 xv = *(const float4*)(x + (size_t)(bm * 64 + r) * 256 + lane * 4);
    float s  = xv.x + xv.y + xv.z + xv.w;
    float s2 = xv.x*xv.x + xv.y*xv.y + xv.z*xv.z + xv.w*xv.w;
#pragma unroll
    for (int mm = 1; mm < 64; mm <<= 1) {
      s  += __shfl_xor(s,  mm, 64);
      s2 += __shfl_xor(s2, mm, 64);
    }
    float mu  = s * (1.0f / 256.0f);
    float var = s2 * (1.0f / 256.0f) - mu * mu;
    float rs  = rsqrtf(var + 1e-5f);
    f16x4 ov;
    ov[0] = (f16)((xv.x - mu) * rs * gv.x + bv4.x);
    ov[1] = (f16)((xv.y - mu) * rs * gv.y + bv4.y);
    ov[2] = (f16)((xv.z - mu) * rs * gv.z + bv4.z);
    ov[3] = (f16)((xv.w - mu) * rs * gv.w + bv4.w);
    *(f16x4*)&As[r][lane * 4] = ov;
  }
  // --- 12 col-tiles ---
  for (int ct = 0; ct < 12; ++ct) {
    const f16* B = ct < 4 ? bq : ct < 8 ? bk : bv;
    int je0 = (ct & 3) * 64;
#pragma unroll
    for (int p = 0; p < 8; ++p) {
      int r = t >> 2, c0 = (t & 3) * 8 + p * 32;
      *(f16x8*)&Bs[r][c0] = *(const f16x8*)(B + (size_t)(je0 + r) * 256 + c0);
    }
    __syncthreads();
    f32x4 acc[2][2] = {};
#pragma unroll
    for (int kt = 0; kt < 8; ++kt) {
      f16x8 a0 = *(const f16x8*)&As[wr * 32 +      l15][kt * 32 + l4 * 8];
      f16x8 a1 = *(const f16x8*)&As[wr * 32 + 16 + l15][kt * 32 + l4 * 8];
      f16x8 b0 = *(const f16x8*)&Bs[wc * 32 +      l15][kt * 32 + l4 * 8];
      f16x8 b1 = *(const f16x8*)&Bs[wc * 32 + 16 + l15][kt * 32 + l4 * 8];
      acc[0][0] = __builtin_amdgcn_mfma_f32_16x16x32_f16(a0, b0, acc[0][0], 0, 0, 0);
      acc[0][1] = __builtin_amdgcn_mfma_f32_16x16x32_f16(a0, b1, acc[0][1], 0, 0, 0);
      acc[1][0] = __builtin_amdgcn_mfma_f32_16x16x32_f16(a1, b0, acc[1][0], 0, 0, 0);
      acc[1][1] = __builtin_amdgcn_mfma_f32_16x16x32_f16(a1, b1, acc[1][1], 0, 0, 0);
    }
    if (ct < 8) {
      f16* dst = ct < 4 ? qo : ko;
#pragma unroll
      for (int mi = 0; mi < 2; ++mi)
#pragma unroll
        for (int ni = 0; ni < 2; ++ni)
#pragma unroll
          for (int r = 0; r < 4; ++r) {
            int row = bm * 64 + wr * 32 + mi * 16 + l4 * 4 + r;
            int col = je0 + wc * 32 + ni * 16 + l15;
            dst[(size_t)row * 256 + col] = (f16)acc[mi][ni][r];
          }
    } else {
      // transpose to vT[m][ch][n] via LDS bounce
#pragma unroll
      for (int mi = 0; mi < 2; ++mi)
#pragma unroll
        for (int ni = 0; ni < 2; ++ni)
#pragma unroll
          for (int r = 0; r < 4; ++r)
            vtmp[wc * 32 + ni * 16 + l15][wr * 32 + mi * 16 + l4 * 4 + r] = (f16)acc[mi][ni][r];
      __syncthreads();
      int ch = t >> 2, np = (t & 3) * 16;
      size_t gdst = ((size_t)(bm >> 2) * 256 + je0 + ch) * 256 + (bm & 3) * 64 + np;
      *(f16x8*)(vT + gdst)     = *(const f16x8*)&vtmp[ch][np];
      *(f16x8*)(vT + gdst + 8) = *(const f16x8*)&vtmp[ch][np + 8];
    }
    __syncthreads();
  }
}

// ---------------- K2: attention (swapped-QK, in-register softmax) ----------------
// Block = (m, h, half): 4 waves x 32 queries. K [256][32] and V^T [32][256]
// staged once (coalesced); flash over 8 key-blocks of 32. Per kb:
// S^T = mfma(K,Q) -> lane holds 16 scores of query i=lane&31; softmax local +
// one shfl_xor(32); P packed f16 + shfl-exchange into PV A-frags; O += P@V^T.
__global__ __launch_bounds__(256, 4) void k_attn(const f16* __restrict__ q,
    const f16* __restrict__ k, const f16* __restrict__ vT, f16* __restrict__ o)
{
  __shared__ f16 ks[256][40];
  __shared__ f16 vt[32][264];
  int bx = blockIdx.x;
  int m = bx >> 4, h = (bx >> 1) & 7, half = bx & 1;
  int t = threadIdx.x, lane = t & 63, w = t >> 6;
  int i32 = lane & 31, hi = lane >> 5;
  size_t rowbase = (size_t)m * 256;
  // stage K [256 x 32]
#pragma unroll
  for (int p = 0; p < 4; ++p) {
    int n = p * 64 + (t >> 2);
    int c0 = (t & 3) * 8;
    *(f16x8*)&ks[n][c0] = *(const f16x8*)(k + (rowbase + n) * 256 + h * 32 + c0);
  }
  // stage V^T [32 x 256] (rows contiguous in vT)
#pragma unroll
  for (int p = 0; p < 4; ++p) {
    int idx = p * 256 + t;
    int c = idx >> 5, nb = (idx & 31) * 8;
    *(f16x8*)&vt[c][nb] = *(const f16x8*)(vT + ((size_t)m * 256 + h * 32 + c) * 256 + nb);
  }
  __syncthreads();
  // Q fragments (held in registers for the whole kernel)
  int qi0 = half * 128 + w * 32;
  const f16* qp = q + (rowbase + qi0 + i32) * 256 + h * 32 + hi * 8;
  f16x8 qf0 = *(const f16x8*)(qp);        // ch  0..15 slice
  f16x8 qf1 = *(const f16x8*)(qp + 16);   // ch 16..31 slice
  f32x16 O = {};
  float m_run = -1e30f, l_run = 0.f;
#pragma unroll 2
  for (int kb = 0; kb < 8; ++kb) {
    f16x8 kf0 = *(const f16x8*)&ks[kb * 32 + i32][hi * 8];
    f16x8 kf1 = *(const f16x8*)&ks[kb * 32 + i32][16 + hi * 8];
    f32x16 s = {};
    s = __builtin_amdgcn_mfma_f32_32x32x16_f16(kf0, qf0, s, 0, 0, 0);
    s = __builtin_amdgcn_mfma_f32_32x32x16_f16(kf1, qf1, s, 0, 0, 0);
    // row max (all 16 regs belong to query i32; partner hi-lane has the rest)
    float pmax = s[0];
#pragma unroll
    for (int r = 1; r < 16; ++r) pmax = fmaxf(pmax, s[r]);
    pmax = fmaxf(pmax, __shfl_xor(pmax, 32, 64));
    if (!__all(pmax - m_run <= 8.f)) {      // defer-max: rescale only on growth
      float m_new = fmaxf(m_run, pmax);
      float f = __builtin_amdgcn_exp2f(m_run - m_new);
      l_run *= f;
#pragma unroll
      for (int r = 0; r < 16; ++r)
        O[r] *= __shfl(f, (r & 3) + 8 * (r >> 2) + 4 * hi, 64);
      m_run = m_new;
    }
    float lsum = 0.f;
#pragma unroll
    for (int r = 0; r < 16; ++r) {
      float e = __builtin_amdgcn_exp2f(s[r] - m_run);
      s[r] = e;
      lsum += e;
    }
    lsum += __shfl_xor(lsum, 32, 64);
    l_run += lsum;
    // pack P to f16 pairs: W0/W1[q'] = P at j = 8q' + 4hi + {0,1}/{2,3}
    int W0[4], W1[4];
#pragma unroll
    for (int qq = 0; qq < 4; ++qq) {
      W0[qq] = pk2(s[4 * qq],     s[4 * qq + 1]);
      W1[qq] = pk2(s[4 * qq + 2], s[4 * qq + 3]);
    }
    // two PV k-steps; A-frag words exchanged within the 2-lane (hi) pair group
#pragma unroll
    for (int ks2 = 0; ks2 < 2; ++ks2) {
      int X0 = W0[2 * ks2], Y0 = W0[2 * ks2 + 1];
      int X1 = W1[2 * ks2], Y1 = W1[2 * ks2 + 1];
      int a0 = __shfl(X0, i32, 64),      b0 = __shfl(Y0, i32, 64);
      int a1 = __shfl(X1, i32, 64),      b1 = __shfl(Y1, i32, 64);
      int a2 = __shfl(X0, i32 + 32, 64), b2 = __shfl(Y0, i32 + 32, 64);
      int a3 = __shfl(X1, i32 + 32, 64), b3 = __shfl(Y1, i32 + 32, 64);
      union { unsigned int ww[4]; f16x8 v; } pa;
      pa.ww[0] = hi ? (unsigned)b0 : (unsigned)a0;
      pa.ww[1] = hi ? (unsigned)b1 : (unsigned)a1;
      pa.ww[2] = hi ? (unsigned)b2 : (unsigned)a2;
      pa.ww[3] = hi ? (unsigned)b3 : (unsigned)a3;
      f16x8 vb = *(const f16x8*)&vt[i32][kb * 32 + ks2 * 16 + hi * 8];
      O = __builtin_amdgcn_mfma_f32_32x32x16_f16(pa.v, vb, O, 0, 0, 0);
    }
  }
  float inv = 1.f / l_run;
#pragma unroll
  for (int r = 0; r < 16; ++r) {
    int i = (r & 3) + 8 * (r >> 2) + 4 * hi;
    float fr = __shfl(inv, i, 64);
    o[(rowbase + (size_t)(qi0 + i)) * 256 + h * 32 + i32] = (f16)(O[r] * fr);
  }
}

// ---------------- K3: output projection ----------------
__global__ __launch_bounds__(256) void k_out(const f16* __restrict__ a,
    const f16* __restrict__ bw, const float* __restrict__ bias,
    float* __restrict__ out)
{
  __shared__ f16 As[64][264];
  __shared__ f16 Bs[64][264];
  int bm = blockIdx.x;
  int t = threadIdx.x, lane = t & 63, w = t >> 6;
  int wr = w >> 1, wc = w & 1;
  int l15 = lane & 15, l4 = lane >> 4;
#pragma unroll
  for (int p = 0; p < 8; ++p) {
    int r = t >> 2, c0 = (t & 3) * 8 + p * 32;
    *(f16x8*)&As[r][c0] = *(const f16x8*)(a + (size_t)(bm * 64 + r) * 256 + c0);
  }
  for (int ct = 0; ct < 4; ++ct) {
    int col0 = ct * 64;
#pragma unroll
    for (int p = 0; p < 8; ++p) {
      int r = t >> 2, c0 = (t & 3) * 8 + p * 32;
      *(f16x8*)&Bs[r][c0] = *(const f16x8*)(bw + (size_t)(col0 + r) * 256 + c0);
    }
    __syncthreads();
    f32x4 acc[2][2] = {};
#pragma unroll
    for (int kt = 0; kt < 8; ++kt) {
      f16x8 a0 = *(const f16x8*)&As[wr * 32 +      l15][kt * 32 + l4 * 8];
      f16x8 a1 = *(const f16x8*)&As[wr * 32 + 16 + l15][kt * 32 + l4 * 8];
      f16x8 b0 = *(const f16x8*)&Bs[wc * 32 +      l15][kt * 32 + l4 * 8];
      f16x8 b1 = *(const f16x8*)&Bs[wc * 32 + 16 + l15][kt * 32 + l4 * 8];
      acc[0][0] = __builtin_amdgcn_mfma_f32_16x16x32_f16(a0, b0, acc[0][0], 0, 0, 0);
      acc[0][1] = __builtin_amdgcn_mfma_f32_16x16x32_f16(a0, b1, acc[0][1], 0, 0, 0);
      acc[1][0] = __builtin_amdgcn_mfma_f32_16x16x32_f16(a1, b0, acc[1][0], 0, 0, 0);
      acc[1][1] = __builtin_amdgcn_mfma_f32_16x16x32_f16(a1, b1, acc[1][1], 0, 0, 0);
    }
#pragma unroll
    for (int mi = 0; mi < 2; ++mi)
#pragma unroll
      for (int ni = 0; ni < 2; ++ni)
#pragma unroll
        for (int r = 0; r < 4; ++r) {
          int row = bm * 64 + wr * 32 + mi * 16 + l4 * 4 + r;
          int col = col0 + wc * 32 + ni * 16 + l15;
          out[(size_t)row * 256 + col] = acc[mi][ni][r] + bias[col];
        }
    __syncthreads();
  }
}

extern "C" void kernel_launch(void* const* d_in, const int* in_sizes, int n_in,
                              void* d_out, int out_size, void* d_ws, size_t ws_size,
                              hipStream_t stream)
{
  const float* x  = (const float*)d_in[0];
  const float* g  = (const float*)d_in[1];
  const float* b  = (const float*)d_in[2];
  const float* wq = (const float*)d_in[3];
  const float* wk = (const float*)d_in[4];
  const float* wv = (const float*)d_in[5];
  const float* wf = (const float*)d_in[6];
  const float* bf = (const float*)d_in[7];
  float* out = (float*)d_out;

  char* ws = (char*)d_ws;
  f16* ah  = (f16*)(ws);                                 // attn output
  f16* qh  = (f16*)(ws + (size_t)16 * 1024 * 1024);
  f16* kh  = (f16*)(ws + (size_t)32 * 1024 * 1024);
  f16* vTh = (f16*)(ws + (size_t)48 * 1024 * 1024);      // [m][ch][n]
  char* wbase = ws + (size_t)64 * 1024 * 1024;
  f16* bq = (f16*)(wbase);
  f16* bk = (f16*)(wbase + 128 * 1024);
  f16* bv = (f16*)(wbase + 256 * 1024);
  f16* bw = (f16*)(wbase + 384 * 1024);

  k_prep <<<1024, 256, 0, stream>>>(wq, wk, wv, wf, bq, bk, bv, bw);
  k_lnqkv<<<512,  256, 0, stream>>>(x, g, b, bq, bk, bv, qh, kh, vTh);
  k_attn <<<2048, 256, 0, stream>>>(qh, kh, vTh, ah);
  k_out  <<<512,  256, 0, stream>>>(ah, bw, bf, out);
}

// Round 5
// 82.234 us; speedup vs baseline: 2.2692x; 1.0221x over previous
//
#include <hip/hip_runtime.h>

typedef _Float16 f16;
typedef _Float16 f16x8 __attribute__((ext_vector_type(8)));
typedef _Float16 f16x4 __attribute__((ext_vector_type(4)));
typedef _Float16 f16x2 __attribute__((ext_vector_type(2)));
typedef float f32x4 __attribute__((ext_vector_type(4)));
typedef float f32x16 __attribute__((ext_vector_type(16)));

#define MDIM 128
#define NDIM 256
#define CDIM 256
#define ROWS (MDIM*NDIM)   // 32768
#define L2E 1.4426950408889634f

// pack two f32 -> f16x2 in one int (k-ascending: low half = first element)
__device__ inline int pk2(float a, float b) {
  union { f16x2 h; int i; } u;
  u.h[0] = (f16)a; u.h[1] = (f16)b;
  return u.i;
}

// ---------------- K0: weight prepack (LDS-transpose tiles) ----------------
// wq/wk/wv -> f16 [je][k], je=h*32+c (orig col j=(je&31)*8+(je>>5)); 1/sqrt(32)
// folded into wq (log2e now applied in f32 at exp time). wf -> f16 [col][ke],
// ke row-permuted. Block = (which, 64 k-rows); coalesced loads, LDS transpose.
__global__ __launch_bounds__(256) void k_prep(
    const float* __restrict__ wq, const float* __restrict__ wk,
    const float* __restrict__ wv, const float* __restrict__ wf,
    f16* __restrict__ bq, f16* __restrict__ bk, f16* __restrict__ bv,
    f16* __restrict__ bw)
{
  __shared__ f16 ld[64][264];
  int which = blockIdx.x >> 2, kb = blockIdx.x & 3;
  int t = threadIdx.x;
  int k0 = kb * 64;
  if (which < 3) {
    const float* W = which == 0 ? wq : which == 1 ? wk : wv;
    f16* dst       = which == 0 ? bq : which == 1 ? bk : bv;
    float sc = which == 0 ? 0.17677669529663689f : 1.0f;
    for (int r = 0; r < 64; ++r)
      ld[r][t] = (f16)(W[(size_t)(k0 + r) * 256 + t] * sc);
    __syncthreads();
    int j = (t & 31) * 8 + (t >> 5);     // source col for output row je=t
#pragma unroll
    for (int rr = 0; rr < 8; ++rr) {
      f16x8 o;
#pragma unroll
      for (int i = 0; i < 8; ++i) o[i] = ld[rr * 8 + i][j];
      *(f16x8*)(dst + (size_t)t * 256 + k0 + rr * 8) = o;
    }
  } else {
    for (int r = 0; r < 64; ++r) {
      int ke = k0 + r;
      int jr = (ke & 31) * 8 + (ke >> 5);
      ld[r][t] = (f16)wf[(size_t)jr * 256 + t];
    }
    __syncthreads();
#pragma unroll
    for (int rr = 0; rr < 8; ++rr) {
      f16x8 o;
#pragma unroll
      for (int i = 0; i < 8; ++i) o[i] = ld[rr * 8 + i][t];
      *(f16x8*)(bw + (size_t)t * 256 + k0 + rr * 8) = o;
    }
  }
}

// ---------------- K1: fused LayerNorm + QKV GEMM ----------------
// Block = 64 rows; As = LN(x) in LDS; 12 col-tiles with register prefetch of
// the next B tile (T14: global loads overlap MFMA of current tile).
__global__ __launch_bounds__(256) void k_lnqkv(const float* __restrict__ x,
    const float* __restrict__ g, const float* __restrict__ bb,
    const f16* __restrict__ bq, const f16* __restrict__ bk, const f16* __restrict__ bv,
    f16* __restrict__ qo, f16* __restrict__ ko, f16* __restrict__ vT)
{
  __shared__ f16 As[64][264];
  __shared__ f16 Bs[64][264];
  __shared__ f16 vtmp[64][72];
  int bm = blockIdx.x;
  int t = threadIdx.x, lane = t & 63, w = t >> 6;
  int wr = w >> 1, wc = w & 1;
  int l15 = lane & 15, l4 = lane >> 4;
  int pr = t >> 2, pc = (t & 3) * 8;      // staging coords
  // issue B(0) prefetch first so it hides under LN
  f16x8 pf[8];
#pragma unroll
  for (int p = 0; p < 8; ++p)
    pf[p] = *(const f16x8*)(bq + (size_t)pr * 256 + pc + p * 32);
  // --- LN: wave w -> rows w*16..w*16+15 ---
  const float4 gv  = *(const float4*)(g + lane * 4);
  const float4 bv4 = *(const float4*)(bb + lane * 4);
#pragma unroll 4
  for (int rr = 0; rr < 16; ++rr) {
    int r = w * 16 + rr;
    const float4 xv = *(const float4*)(x + (size_t)(bm * 64 + r) * 256 + lane * 4);
    float s  = xv.x + xv.y + xv.z + xv.w;
    float s2 = xv.x*xv.x + xv.y*xv.y + xv.z*xv.z + xv.w*xv.w;
#pragma unroll
    for (int mm = 1; mm < 64; mm <<= 1) {
      s  += __shfl_xor(s,  mm, 64);
      s2 += __shfl_xor(s2, mm, 64);
    }
    float mu  = s * (1.0f / 256.0f);
    float var = s2 * (1.0f / 256.0f) - mu * mu;
    float rs  = rsqrtf(var + 1e-5f);
    f16x4 ov;
    ov[0] = (f16)((xv.x - mu) * rs * gv.x + bv4.x);
    ov[1] = (f16)((xv.y - mu) * rs * gv.y + bv4.y);
    ov[2] = (f16)((xv.z - mu) * rs * gv.z + bv4.z);
    ov[3] = (f16)((xv.w - mu) * rs * gv.w + bv4.w);
    *(f16x4*)&As[r][lane * 4] = ov;
  }
  // --- 12 col-tiles ---
  for (int ct = 0; ct < 12; ++ct) {
    int je0 = (ct & 3) * 64;
#pragma unroll
    for (int p = 0; p < 8; ++p)
      *(f16x8*)&Bs[pr][pc + p * 32] = pf[p];
    __syncthreads();
    if (ct < 11) {
      const f16* Bn = (ct + 1) < 4 ? bq : (ct + 1) < 8 ? bk : bv;
      int je0n = ((ct + 1) & 3) * 64;
#pragma unroll
      for (int p = 0; p < 8; ++p)
        pf[p] = *(const f16x8*)(Bn + (size_t)(je0n + pr) * 256 + pc + p * 32);
    }
    f32x4 acc[2][2] = {};
#pragma unroll
    for (int kt = 0; kt < 8; ++kt) {
      f16x8 a0 = *(const f16x8*)&As[wr * 32 +      l15][kt * 32 + l4 * 8];
      f16x8 a1 = *(const f16x8*)&As[wr * 32 + 16 + l15][kt * 32 + l4 * 8];
      f16x8 b0 = *(const f16x8*)&Bs[wc * 32 +      l15][kt * 32 + l4 * 8];
      f16x8 b1 = *(const f16x8*)&Bs[wc * 32 + 16 + l15][kt * 32 + l4 * 8];
      acc[0][0] = __builtin_amdgcn_mfma_f32_16x16x32_f16(a0, b0, acc[0][0], 0, 0, 0);
      acc[0][1] = __builtin_amdgcn_mfma_f32_16x16x32_f16(a0, b1, acc[0][1], 0, 0, 0);
      acc[1][0] = __builtin_amdgcn_mfma_f32_16x16x32_f16(a1, b0, acc[1][0], 0, 0, 0);
      acc[1][1] = __builtin_amdgcn_mfma_f32_16x16x32_f16(a1, b1, acc[1][1], 0, 0, 0);
    }
    if (ct < 8) {
      f16* dst = ct < 4 ? qo : ko;
#pragma unroll
      for (int mi = 0; mi < 2; ++mi)
#pragma unroll
        for (int ni = 0; ni < 2; ++ni)
#pragma unroll
          for (int r = 0; r < 4; ++r) {
            int row = bm * 64 + wr * 32 + mi * 16 + l4 * 4 + r;
            int col = je0 + wc * 32 + ni * 16 + l15;
            dst[(size_t)row * 256 + col] = (f16)acc[mi][ni][r];
          }
    } else {
      // transpose to vT[m][ch][n] via LDS bounce
#pragma unroll
      for (int mi = 0; mi < 2; ++mi)
#pragma unroll
        for (int ni = 0; ni < 2; ++ni)
#pragma unroll
          for (int r = 0; r < 4; ++r)
            vtmp[wc * 32 + ni * 16 + l15][wr * 32 + mi * 16 + l4 * 4 + r] = (f16)acc[mi][ni][r];
      __syncthreads();
      int ch = t >> 2, np = (t & 3) * 16;
      size_t gdst = ((size_t)(bm >> 2) * 256 + je0 + ch) * 256 + (bm & 3) * 64 + np;
      *(f16x8*)(vT + gdst)     = *(const f16x8*)&vtmp[ch][np];
      *(f16x8*)(vT + gdst + 8) = *(const f16x8*)&vtmp[ch][np + 8];
    }
    __syncthreads();
  }
}

// ---------------- K2: attention (block = (m,h), 8 waves x 32 queries) ----------------
__global__ __launch_bounds__(512, 4) void k_attn(const f16* __restrict__ q,
    const f16* __restrict__ k, const f16* __restrict__ vT, f16* __restrict__ o)
{
  __shared__ f16 ks[256][40];
  __shared__ f16 vt[32][264];
  int bx = blockIdx.x;
  int m = bx >> 3, h = bx & 7;
  int t = threadIdx.x, lane = t & 63, w = t >> 6;   // w in 0..7
  int i32 = lane & 31, hi = lane >> 5;
  size_t rowbase = (size_t)m * 256;
  // stage K [256 x 32]
#pragma unroll
  for (int p = 0; p < 2; ++p) {
    int n = p * 128 + (t >> 2);
    int c0 = (t & 3) * 8;
    *(f16x8*)&ks[n][c0] = *(const f16x8*)(k + (rowbase + n) * 256 + h * 32 + c0);
  }
  // stage V^T [32 x 256]
#pragma unroll
  for (int p = 0; p < 2; ++p) {
    int idx = p * 512 + t;
    int c = idx >> 5, nb = (idx & 31) * 8;
    *(f16x8*)&vt[c][nb] = *(const f16x8*)(vT + ((size_t)m * 256 + h * 32 + c) * 256 + nb);
  }
  __syncthreads();
  int qi0 = w * 32;
  const f16* qp = q + (rowbase + qi0 + i32) * 256 + h * 32 + hi * 8;
  f16x8 qf0 = *(const f16x8*)(qp);
  f16x8 qf1 = *(const f16x8*)(qp + 16);
  f32x16 O = {};
  float m_run = -1e30f, l_run = 0.f;
#pragma unroll 2
  for (int kb = 0; kb < 8; ++kb) {
    f16x8 kf0 = *(const f16x8*)&ks[kb * 32 + i32][hi * 8];
    f16x8 kf1 = *(const f16x8*)&ks[kb * 32 + i32][16 + hi * 8];
    f32x16 s = {};
    __builtin_amdgcn_s_setprio(1);
    s = __builtin_amdgcn_mfma_f32_32x32x16_f16(kf0, qf0, s, 0, 0, 0);
    s = __builtin_amdgcn_mfma_f32_32x32x16_f16(kf1, qf1, s, 0, 0, 0);
    __builtin_amdgcn_s_setprio(0);
#pragma unroll
    for (int r = 0; r < 16; ++r) s[r] *= L2E;    // exp2 domain (f32, not folded)
    float pmax = s[0];
#pragma unroll
    for (int r = 1; r < 16; ++r) pmax = fmaxf(pmax, s[r]);
    pmax = fmaxf(pmax, __shfl_xor(pmax, 32, 64));
    if (!__all(pmax - m_run <= 8.f)) {           // defer-max
      float m_new = fmaxf(m_run, pmax);
      float f = __builtin_amdgcn_exp2f(m_run - m_new);
      l_run *= f;
#pragma unroll
      for (int r = 0; r < 16; ++r)
        O[r] *= __shfl(f, (r & 3) + 8 * (r >> 2) + 4 * hi, 64);
      m_run = m_new;
    }
    float lsum = 0.f;
#pragma unroll
    for (int r = 0; r < 16; ++r) {
      float e = __builtin_amdgcn_exp2f(s[r] - m_run);
      s[r] = e;
      lsum += e;
    }
    lsum += __shfl_xor(lsum, 32, 64);
    l_run += lsum;
    int W0[4], W1[4];
#pragma unroll
    for (int qq = 0; qq < 4; ++qq) {
      W0[qq] = pk2(s[4 * qq],     s[4 * qq + 1]);
      W1[qq] = pk2(s[4 * qq + 2], s[4 * qq + 3]);
    }
#pragma unroll
    for (int ks2 = 0; ks2 < 2; ++ks2) {
      int X0 = W0[2 * ks2], Y0 = W0[2 * ks2 + 1];
      int X1 = W1[2 * ks2], Y1 = W1[2 * ks2 + 1];
      int a0 = __shfl(X0, i32, 64),      b0 = __shfl(Y0, i32, 64);
      int a1 = __shfl(X1, i32, 64),      b1 = __shfl(Y1, i32, 64);
      int a2 = __shfl(X0, i32 + 32, 64), b2 = __shfl(Y0, i32 + 32, 64);
      int a3 = __shfl(X1, i32 + 32, 64), b3 = __shfl(Y1, i32 + 32, 64);
      union { unsigned int ww[4]; f16x8 v; } pa;
      pa.ww[0] = hi ? (unsigned)b0 : (unsigned)a0;
      pa.ww[1] = hi ? (unsigned)b1 : (unsigned)a1;
      pa.ww[2] = hi ? (unsigned)b2 : (unsigned)a2;
      pa.ww[3] = hi ? (unsigned)b3 : (unsigned)a3;
      f16x8 vb = *(const f16x8*)&vt[i32][kb * 32 + ks2 * 16 + hi * 8];
      __builtin_amdgcn_s_setprio(1);
      O = __builtin_amdgcn_mfma_f32_32x32x16_f16(pa.v, vb, O, 0, 0, 0);
      __builtin_amdgcn_s_setprio(0);
    }
  }
  float inv = 1.f / l_run;
#pragma unroll
  for (int r = 0; r < 16; ++r) {
    int i = (r & 3) + 8 * (r >> 2) + 4 * hi;
    float fr = __shfl(inv, i, 64);
    o[(rowbase + (size_t)(qi0 + i)) * 256 + h * 32 + i32] = (f16)(O[r] * fr);
  }
}

// ---------------- K3: output projection (with B register prefetch) ----------------
__global__ __launch_bounds__(256) void k_out(const f16* __restrict__ a,
    const f16* __restrict__ bw, const float* __restrict__ bias,
    float* __restrict__ out)
{
  __shared__ f16 As[64][264];
  __shared__ f16 Bs[64][264];
  int bm = blockIdx.x;
  int t = threadIdx.x, lane = t & 63, w = t >> 6;
  int wr = w >> 1, wc = w & 1;
  int l15 = lane & 15, l4 = lane >> 4;
  int pr = t >> 2, pc = (t & 3) * 8;
  f16x8 pf[8];
#pragma unroll
  for (int p = 0; p < 8; ++p)
    pf[p] = *(const f16x8*)(bw + (size_t)pr * 256 + pc + p * 32);
#pragma unroll
  for (int p = 0; p < 8; ++p)
    *(f16x8*)&As[pr][pc + p * 32] = *(const f16x8*)(a + (size_t)(bm * 64 + pr) * 256 + pc + p * 32);
  for (int ct = 0; ct < 4; ++ct) {
    int col0 = ct * 64;
#pragma unroll
    for (int p = 0; p < 8; ++p)
      *(f16x8*)&Bs[pr][pc + p * 32] = pf[p];
    __syncthreads();
    if (ct < 3) {
#pragma unroll
      for (int p = 0; p < 8; ++p)
        pf[p] = *(const f16x8*)(bw + (size_t)((ct + 1) * 64 + pr) * 256 + pc + p * 32);
    }
    f32x4 acc[2][2] = {};
#pragma unroll
    for (int kt = 0; kt < 8; ++kt) {
      f16x8 a0 = *(const f16x8*)&As[wr * 32 +      l15][kt * 32 + l4 * 8];
      f16x8 a1 = *(const f16x8*)&As[wr * 32 + 16 + l15][kt * 32 + l4 * 8];
      f16x8 b0 = *(const f16x8*)&Bs[wc * 32 +      l15][kt * 32 + l4 * 8];
      f16x8 b1 = *(const f16x8*)&Bs[wc * 32 + 16 + l15][kt * 32 + l4 * 8];
      acc[0][0] = __builtin_amdgcn_mfma_f32_16x16x32_f16(a0, b0, acc[0][0], 0, 0, 0);
      acc[0][1] = __builtin_amdgcn_mfma_f32_16x16x32_f16(a0, b1, acc[0][1], 0, 0, 0);
      acc[1][0] = __builtin_amdgcn_mfma_f32_16x16x32_f16(a1, b0, acc[1][0], 0, 0, 0);
      acc[1][1] = __builtin_amdgcn_mfma_f32_16x16x32_f16(a1, b1, acc[1][1], 0, 0, 0);
    }
#pragma unroll
    for (int mi = 0; mi < 2; ++mi)
#pragma unroll
      for (int ni = 0; ni < 2; ++ni)
#pragma unroll
        for (int r = 0; r < 4; ++r) {
          int row = bm * 64 + wr * 32 + mi * 16 + l4 * 4 + r;
          int col = col0 + wc * 32 + ni * 16 + l15;
          out[(size_t)row * 256 + col] = acc[mi][ni][r] + bias[col];
        }
    __syncthreads();
  }
}

extern "C" void kernel_launch(void* const* d_in, const int* in_sizes, int n_in,
                              void* d_out, int out_size, void* d_ws, size_t ws_size,
                              hipStream_t stream)
{
  const float* x  = (const float*)d_in[0];
  const float* g  = (const float*)d_in[1];
  const float* b  = (const float*)d_in[2];
  const float* wq = (const float*)d_in[3];
  const float* wk = (const float*)d_in[4];
  const float* wv = (const float*)d_in[5];
  const float* wf = (const float*)d_in[6];
  const float* bf = (const float*)d_in[7];
  float* out = (float*)d_out;

  char* ws = (char*)d_ws;
  f16* ah  = (f16*)(ws);                                 // attn output
  f16* qh  = (f16*)(ws + (size_t)16 * 1024 * 1024);
  f16* kh  = (f16*)(ws + (size_t)32 * 1024 * 1024);
  f16* vTh = (f16*)(ws + (size_t)48 * 1024 * 1024);      // [m][ch][n]
  char* wbase = ws + (size_t)64 * 1024 * 1024;
  f16* bq = (f16*)(wbase);
  f16* bk = (f16*)(wbase + 128 * 1024);
  f16* bv = (f16*)(wbase + 256 * 1024);
  f16* bw = (f16*)(wbase + 384 * 1024);

  k_prep <<<16,   256, 0, stream>>>(wq, wk, wv, wf, bq, bk, bv, bw);
  k_lnqkv<<<512,  256, 0, stream>>>(x, g, b, bq, bk, bv, qh, kh, vTh);
  k_attn <<<1024, 512, 0, stream>>>(qh, kh, vTh, ah);
  k_out  <<<512,  256, 0, stream>>>(ah, bw, bf, out);
}